// Round 1
// baseline (1154.103 us; speedup 1.0000x reference)
//
#include <hip/hip_runtime.h>

typedef unsigned short ushort_t;
using floatx4 = __attribute__((ext_vector_type(4))) float;
using shortx8 = __attribute__((ext_vector_type(8))) short;

#define NROWS_E 131072            // B*V*V per edge tensor
#define E_ELEMS 33554432          // NROWS_E * 256
#define H_ROWS  512               // B*V
#define H_ELEMS 131072            // H_ROWS * 256

__device__ __forceinline__ ushort_t f2bf(float f) {
    union { float f; unsigned int u; } x; x.f = f;
    unsigned int r = (x.u + 0x7FFFu + ((x.u >> 16) & 1u)) >> 16;
    return (ushort_t)r;
}

// ---------------- K0: convert W slots {8,11,14} to bf16 ----------------
__global__ void k_convW(const float* __restrict__ Ws, ushort_t* __restrict__ Wb) {
    int idx = blockIdx.x * 256 + threadIdx.x;     // 196608 total
    int t = idx >> 16;
    int r = idx & 65535;
    int slot = (t == 0) ? 8 : (t == 1) ? 11 : 14;
    Wb[idx] = f2bf(Ws[slot * 65536 + r]);
}

// ---------------- K1: 12 small linears (fp32 tiled 64x64) ----------------
__launch_bounds__(256)
__global__ void k_lin(const float* __restrict__ hsc, const float* __restrict__ hst,
                      const float* __restrict__ Ws, const float* __restrict__ bs,
                      float* __restrict__ tH) {
    // grid = 12 slots * 8 mtiles * 4 ntiles = 384
    int bx = blockIdx.x;
    int s = bx >> 5; int rem = bx & 31; int mt = rem >> 2; int nt = rem & 3;
    const int wsl[12] = {0,1,2,3,4,5,6,7,9,10,12,13};
    const int xst[12] = {0,1,0,1,0,1,0,1,0,0,1,1};
    int wslot = wsl[s];
    const float* x = xst[s] ? hst : hsc;
    int m0 = mt * 64, n0 = nt * 64;
    __shared__ float Xs[64][33];
    __shared__ float Wt[64][33];
    int tid = threadIdx.x;
    int tn = tid & 15, tm = tid >> 4;
    float acc[4][4] = {};
    for (int kk = 0; kk < 8; ++kk) {
        int k0 = kk * 32;
        #pragma unroll
        for (int u = tid; u < 2048; u += 256) {
            int r = u >> 5, k = u & 31;
            Xs[r][k] = x[(m0 + r) * 256 + k0 + k];
            Wt[r][k] = Ws[wslot * 65536 + (n0 + r) * 256 + k0 + k];
        }
        __syncthreads();
        #pragma unroll
        for (int k = 0; k < 32; ++k) {
            float a[4], b[4];
            #pragma unroll
            for (int i = 0; i < 4; ++i) a[i] = Xs[tm*4+i][k];
            #pragma unroll
            for (int j = 0; j < 4; ++j) b[j] = Wt[tn*4+j][k];
            #pragma unroll
            for (int i = 0; i < 4; ++i)
                #pragma unroll
                for (int j = 0; j < 4; ++j) acc[i][j] += a[i]*b[j];
        }
        __syncthreads();
    }
    #pragma unroll
    for (int i = 0; i < 4; ++i)
        #pragma unroll
        for (int j = 0; j < 4; ++j) {
            int n = n0 + tn*4 + j;
            tH[(long)s * H_ELEMS + (long)(m0 + tm*4 + i) * 256 + n] = acc[i][j] + bs[wslot*256 + n];
        }
}

// ---------------- K2: edge pass B — MFMA GEMM + e2 store + stats + gated agg --------
__launch_bounds__(256, 3)
__global__ void k_passb(const float* __restrict__ e_bi, const float* __restrict__ e_sc,
                        const float* __restrict__ e_st,
                        const float* __restrict__ tH, const ushort_t* __restrict__ Wb,
                        const float* __restrict__ bs,
                        float* __restrict__ outE,        // d_out + 262144
                        float* __restrict__ accSc, float* __restrict__ accSt,
                        float* __restrict__ S1, float* __restrict__ S2) {
    int bx = blockIdx.x;
    int t = bx >> 11;              // 2048 m-tiles / tensor
    int rem = bx & 2047;
    int b = rem >> 10;
    int rem2 = rem & 1023;
    int i0 = (rem2 >> 5) * 8;
    int j0 = (rem2 & 31) * 8;

    const float *e, *tA, *tB, *wj, *wi;
    int doSj, doSi, slotC;
    if (t == 0)      { e = e_bi; tA = tH + 6L*H_ELEMS; tB = tH + 7L*H_ELEMS; wj = tH + 3L*H_ELEMS; wi = tH + 2L*H_ELEMS; doSj = 1; doSi = 1; slotC = 8; }
    else if (t == 1) { e = e_sc; tA = tH + 8L*H_ELEMS; tB = tH + 9L*H_ELEMS; wj = tH + 4L*H_ELEMS; wi = tH;             doSj = 1; doSi = 0; slotC = 11; }
    else             { e = e_st; tA = tH + 10L*H_ELEMS; tB = tH + 11L*H_ELEMS; wj = tH;            wi = tH + 5L*H_ELEMS; doSj = 0; doSi = 1; slotC = 14; }

    __shared__ ushort_t As[64 * 32];     // 4 KB
    __shared__ ushort_t Bs[256 * 32];    // 16 KB
    __shared__ float tAs[8 * 256];       // 8 KB
    __shared__ float tBs[8 * 256];       // 8 KB (includes bias C)
    __shared__ float wjs[8 * 256];       // 8 KB
    __shared__ float wis[8 * 256];       // 8 KB  => total 52 KB

    int tid = threadIdx.x;
    // stage epilogue arrays (tB gets C-bias folded in)
    #pragma unroll
    for (int u = tid; u < 2048; u += 256) {
        int r = u >> 8, c = u & 255;
        tAs[u] = tA[(long)(b*256 + i0 + r) * 256 + c];
        tBs[u] = tB[(long)(b*256 + j0 + r) * 256 + c] + bs[slotC*256 + c];
        wjs[u] = wj[(long)(b*256 + j0 + r) * 256 + c];
        wis[u] = wi[(long)(b*256 + i0 + r) * 256 + c];
    }

    const ushort_t* WbT = Wb + (long)t * 65536;
    int lane = tid & 63;
    int wave_n = tid >> 6;
    int fc = lane & 15;
    int quad = lane >> 4;

    floatx4 acc[4][4];
    #pragma unroll
    for (int i = 0; i < 4; ++i)
        #pragma unroll
        for (int j = 0; j < 4; ++j) acc[i][j] = (floatx4){0.f, 0.f, 0.f, 0.f};

    // A-stage coords: thread -> (row, 8-wide k chunk)
    int slr = tid >> 2;
    int skq = (tid & 3) * 8;
    int siloc = slr >> 3, sjloc = slr & 7;
    const float* arow = e + ((long)(b*256 + i0 + siloc) * 256 + (j0 + sjloc)) * 256;

    for (int kk = 0; kk < 8; ++kk) {
        int k0 = kk * 32;
        // stage A: 64x32 f32 -> bf16
        float4 f0 = *(const float4*)(arow + k0 + skq);
        float4 f1 = *(const float4*)(arow + k0 + skq + 4);
        shortx8 pk;
        pk[0] = (short)f2bf(f0.x); pk[1] = (short)f2bf(f0.y);
        pk[2] = (short)f2bf(f0.z); pk[3] = (short)f2bf(f0.w);
        pk[4] = (short)f2bf(f1.x); pk[5] = (short)f2bf(f1.y);
        pk[6] = (short)f2bf(f1.z); pk[7] = (short)f2bf(f1.w);
        *(shortx8*)&As[slr*32 + skq] = pk;
        // stage B: 256x32 bf16 (row n = tid)
        const uint4* bsrc = (const uint4*)(WbT + (long)tid * 256 + k0);
        uint4* bdst = (uint4*)&Bs[tid * 32];
        #pragma unroll
        for (int q = 0; q < 4; ++q) bdst[q] = bsrc[q];
        __syncthreads();
        shortx8 af[4];
        #pragma unroll
        for (int mt = 0; mt < 4; ++mt)
            af[mt] = *(const shortx8*)&As[(mt*16 + fc)*32 + quad*8];
        #pragma unroll
        for (int nt = 0; nt < 4; ++nt) {
            shortx8 bf = *(const shortx8*)&Bs[(wave_n*64 + nt*16 + fc)*32 + quad*8];
            #pragma unroll
            for (int mt = 0; mt < 4; ++mt)
                acc[mt][nt] = __builtin_amdgcn_mfma_f32_16x16x32_bf16(af[mt], bf, acc[mt][nt], 0, 0, 0);
        }
        __syncthreads();
    }

    // epilogue
    float s1[4] = {0,0,0,0}, s2[4] = {0,0,0,0};
    float sst[4][4] = {};
    long outBase = (long)t * E_ELEMS;
    #pragma unroll
    for (int nt = 0; nt < 4; ++nt) {
        int cloc = wave_n*64 + nt*16 + fc;
        #pragma unroll
        for (int mt = 0; mt < 4; ++mt) {
            int iloc = 2*mt + (quad >> 1);
            float tAv = tAs[iloc*256 + cloc];
            float wiv = wis[iloc*256 + cloc];
            float p = 0.f;
            #pragma unroll
            for (int r = 0; r < 4; ++r) {
                int jloc = (quad & 1)*4 + r;
                float v = acc[mt][nt][r] + tAv + tBs[jloc*256 + cloc];
                s1[nt] += v; s2[nt] += v*v;
                float g = 1.f / (1.f + __expf(-v));
                long grow = (long)(b*256 + i0 + iloc) * 256 + (j0 + jloc);
                outE[outBase + grow*256 + cloc] = v;
                if (doSj) p += g * wjs[jloc*256 + cloc];
                if (doSi) sst[nt][r] += g * wiv;
            }
            if (doSj) {
                p += __shfl_xor(p, 16);
                if ((quad & 1) == 0)
                    atomicAdd(&accSc[(long)(b*256 + i0 + iloc)*256 + cloc], p);
            }
        }
        if (doSi) {
            #pragma unroll
            for (int r = 0; r < 4; ++r) {
                float vv = sst[nt][r] + __shfl_xor(sst[nt][r], 32);
                if (quad < 2) {
                    int jloc = (quad & 1)*4 + r;
                    atomicAdd(&accSt[(long)(b*256 + j0 + jloc)*256 + cloc], vv);
                }
            }
        }
        float a1 = s1[nt]; a1 += __shfl_xor(a1, 16); a1 += __shfl_xor(a1, 32);
        float a2 = s2[nt]; a2 += __shfl_xor(a2, 16); a2 += __shfl_xor(a2, 32);
        if (quad == 0) {
            atomicAdd(&S1[t*256 + cloc], a1);
            atomicAdd(&S2[t*256 + cloc], a2);
        }
    }
}

// ---------------- K_bnp: edge BN affine params ----------------
__global__ void k_bnp(const float* __restrict__ S1, const float* __restrict__ S2,
                      const float* __restrict__ ge, const float* __restrict__ be,
                      float* __restrict__ scale, float* __restrict__ shift) {
    int t = blockIdx.x, c = threadIdx.x;
    float N = (float)NROWS_E;
    float mean = S1[t*256 + c] / N;
    float var = S2[t*256 + c] / N - mean*mean;
    float rs = rsqrtf(var + 1e-5f);
    float sc = ge[c] * rs;
    scale[t*256 + c] = sc;
    shift[t*256 + c] = be[c] - sc * mean;
}

// ---------------- K3: h finalize (BN over 512 rows + relu + residual) ----------------
__global__ void k_hfin(const float* __restrict__ tH, const float* __restrict__ accSc,
                       const float* __restrict__ accSt,
                       const float* __restrict__ hsc, const float* __restrict__ hst,
                       const float* __restrict__ gh, const float* __restrict__ bh,
                       float* __restrict__ outp) {
    int tau = blockIdx.x >> 8;
    int c = blockIdx.x & 255;
    const float* U = tH + (tau ? (long)H_ELEMS : 0L);
    const float* A = tau ? accSt : accSc;
    const float* hin = tau ? hst : hsc;
    int lane = threadIdx.x;   // 64
    float v[8]; float s1 = 0.f, s2 = 0.f;
    #pragma unroll
    for (int k = 0; k < 8; ++k) {
        int row = lane + k*64;
        float x = U[(long)row*256 + c] + A[(long)row*256 + c];
        v[k] = x; s1 += x; s2 += x*x;
    }
    #pragma unroll
    for (int off = 1; off < 64; off <<= 1) { s1 += __shfl_xor(s1, off); s2 += __shfl_xor(s2, off); }
    float mean = s1 / 512.f;
    float var = s2 / 512.f - mean*mean;
    float rs = rsqrtf(var + 1e-5f);
    float gc = gh[c], bc = bh[c];
    #pragma unroll
    for (int k = 0; k < 8; ++k) {
        int row = lane + k*64;
        float y = gc * (v[k] - mean) * rs + bc;
        outp[(long)tau*H_ELEMS + (long)row*256 + c] = hin[(long)row*256 + c] + fmaxf(y, 0.f);
    }
}

// ---------------- K4: edge finalize (in-place BN+relu+residual) ----------------
__launch_bounds__(256)
__global__ void k_efin(const float* __restrict__ e_bi, const float* __restrict__ e_sc,
                       const float* __restrict__ e_st,
                       const float* __restrict__ scale, const float* __restrict__ shift,
                       float* __restrict__ outE) {
    long idx4 = (long)blockIdx.x * 256 + threadIdx.x;
    long fi = idx4 * 4;
    int t = (int)(fi >> 25);
    long within = fi & (long)(E_ELEMS - 1);
    int c = (int)(fi & 255);
    const float* ein = (t == 0) ? e_bi : (t == 1) ? e_sc : e_st;
    float4 sc4 = *(const float4*)&scale[t*256 + c];
    float4 sh4 = *(const float4*)&shift[t*256 + c];
    float4 v = *(const float4*)&outE[fi];
    float4 e4 = *(const float4*)&ein[within];
    float4 r;
    r.x = e4.x + fmaxf(sc4.x*v.x + sh4.x, 0.f);
    r.y = e4.y + fmaxf(sc4.y*v.y + sh4.y, 0.f);
    r.z = e4.z + fmaxf(sc4.z*v.z + sh4.z, 0.f);
    r.w = e4.w + fmaxf(sc4.w*v.w + sh4.w, 0.f);
    *(float4*)&outE[fi] = r;
}

extern "C" void kernel_launch(void* const* d_in, const int* in_sizes, int n_in,
                              void* d_out, int out_size, void* d_ws, size_t ws_size,
                              hipStream_t stream) {
    (void)in_sizes; (void)n_in; (void)out_size; (void)ws_size;
    const float* h_sc = (const float*)d_in[0];
    const float* h_st = (const float*)d_in[1];
    const float* bi_e = (const float*)d_in[2];
    const float* sc_e = (const float*)d_in[4];
    const float* st_e = (const float*)d_in[6];
    const float* Ws   = (const float*)d_in[8];
    const float* bs   = (const float*)d_in[9];
    const float* gh   = (const float*)d_in[10];
    const float* bh   = (const float*)d_in[11];
    const float* ge   = (const float*)d_in[12];
    const float* be   = (const float*)d_in[13];
    float* out = (float*)d_out;

    float* ws = (float*)d_ws;
    float* tH      = ws;                 // 12*131072
    float* accSc   = ws + 1572864;       // 131072
    float* accSt   = ws + 1703936;       // 131072
    float* S1      = ws + 1835008;       // 768
    float* S2      = ws + 1835776;       // 768
    float* bnScale = ws + 1836544;       // 768
    float* bnShift = ws + 1837312;       // 768
    ushort_t* Wb   = (ushort_t*)(ws + 1838080);  // 196608 bf16

    // zero: accSc, accSt, S1, S2 (contiguous)
    hipMemsetAsync(accSc, 0, (size_t)(131072*2 + 1536) * sizeof(float), stream);
    k_convW<<<768, 256, 0, stream>>>(Ws, Wb);
    k_lin<<<384, 256, 0, stream>>>(h_sc, h_st, Ws, bs, tH);
    k_passb<<<6144, 256, 0, stream>>>(bi_e, sc_e, st_e, tH, Wb, bs,
                                      out + 262144, accSc, accSt, S1, S2);
    k_bnp<<<3, 256, 0, stream>>>(S1, S2, ge, be, bnScale, bnShift);
    k_hfin<<<512, 64, 0, stream>>>(tH, accSc, accSt, h_sc, h_st, gh, bh, out);
    k_efin<<<98304, 256, 0, stream>>>(bi_e, sc_e, st_e, bnScale, bnShift, out + 262144);
}